// Round 1
// baseline (84.846 us; speedup 1.0000x reference)
//
#include <hip/hip_runtime.h>

// Problem constants (match reference)
constexpr int B = 32, T = 512, F = 300, S = 256, KMAX = 32;
constexpr int T_PER_BLOCK = 16;   // t-values handled per block (16 rows * 300 f32 = 19.2 KB LDS)

// out[b,t,s] = count of k with thresholds[s,k] <= features[b,t,slot_ids[s]]
// (valid rows sorted ascending, invalid entries are +inf -> never counted)
//
// v2: replace the per-lane divergent global gather (64 scattered addresses/wave
// inside a 1200B feature row -> TA serialization) with:
//   coalesced float4 global->LDS staging of the block's 16 contiguous rows,
//   then the random-slot gather served by the LDS 32-bank crossbar.
__global__ __launch_bounds__(256, 4) void SequenceBucketPreprocessor_kernel(
    const float* __restrict__ features,    // (B,T,F)
    const float* __restrict__ thresholds,  // (S,KMAX)
    const int*   __restrict__ slot_ids,    // (S,)
    int*         __restrict__ out)         // (B,T,S) int32
{
    __shared__ float lds[T_PER_BLOCK * F];          // 4800 floats = 19.2 KB

    const int s   = threadIdx.x;                    // one s per thread (S==256==blockDim)
    const int bt0 = blockIdx.x * T_PER_BLOCK;       // first flattened (b*T+t) index

    // ---- stage: 16 contiguous feature rows -> LDS, fully coalesced float4 ----
    // Block's region is contiguous: features[bt0*F .. bt0*F + 4800)
    constexpr int NCHUNK = T_PER_BLOCK * F / 4;     // 1200 float4 chunks
    const float4* gsrc = reinterpret_cast<const float4*>(features + bt0 * F);
    float4*       ldst = reinterpret_cast<float4*>(lds);
    #pragma unroll
    for (int r = 0; r < (NCHUNK + S - 1) / S; ++r) {  // 5 rounds
        const int i = r * S + s;
        if (i < NCHUNK) ldst[i] = gsrc[i];
    }

    // ---- this thread's 32 thresholds -> registers (overlaps with staging) ----
    float thr[KMAX];
    const float4* trow = reinterpret_cast<const float4*>(thresholds + s * KMAX);
    #pragma unroll
    for (int q = 0; q < KMAX / 4; ++q) {
        float4 v = trow[q];
        thr[q * 4 + 0] = v.x;
        thr[q * 4 + 1] = v.y;
        thr[q * 4 + 2] = v.z;
        thr[q * 4 + 3] = v.w;
    }
    const int slot = slot_ids[s];

    __syncthreads();

    // ---- compute: gather from LDS, 32 compares, coalesced stores ----
    #pragma unroll
    for (int j0 = 0; j0 < T_PER_BLOCK; j0 += 8) {
        float v[8];
        #pragma unroll
        for (int j = 0; j < 8; ++j)
            v[j] = lds[(j0 + j) * F + slot];        // ds_read_b32, imm offset j*1200B

        int c[8] = {0, 0, 0, 0, 0, 0, 0, 0};
        #pragma unroll
        for (int k = 0; k < KMAX; ++k) {
            #pragma unroll
            for (int j = 0; j < 8; ++j)
                c[j] += (thr[k] <= v[j]);
        }

        #pragma unroll
        for (int j = 0; j < 8; ++j)
            out[(bt0 + j0 + j) * S + s] = c[j];     // coalesced dword stores along s
    }
}

extern "C" void kernel_launch(void* const* d_in, const int* in_sizes, int n_in,
                              void* d_out, int out_size, void* d_ws, size_t ws_size,
                              hipStream_t stream) {
    const float* features   = (const float*)d_in[0];  // (B,T,F) f32
    const float* thresholds = (const float*)d_in[1];  // (S,KMAX) f32
    const int*   slot_ids   = (const int*)d_in[2];    // (S,) i32
    // d_in[3] = bucket_nums: not needed (encoded in +inf padding of thresholds)
    int* out = (int*)d_out;                            // (B,T,S) i32

    const int n_bt   = B * T;                          // 16384
    const int blocks = n_bt / T_PER_BLOCK;             // 1024 = 4 blocks/CU exactly
    SequenceBucketPreprocessor_kernel<<<dim3(blocks), dim3(S), 0, stream>>>(
        features, thresholds, slot_ids, out);
}

// Round 3
// 81.349 us; speedup vs baseline: 1.0430x; 1.0430x over previous
//
#include <hip/hip_runtime.h>

// Problem constants (match reference)
constexpr int B = 32, T = 512, F = 300, S = 256, KMAX = 32;
constexpr int T_PER_BLOCK = 16;   // t-values handled per block

// out[b,t,s] = count of k with thresholds[s,k] <= features[b,t,slot_ids[s]]
// (valid rows sorted ascending, invalid entries are +inf -> never counted)
//
// v3 (resubmit after container infra failure; no code change):
//   direct-gather structure (v1 beat the LDS-staged v2: gather not bottleneck)
//   - all 16 feature gathers issued up-front (16 outstanding loads/thread)
//   - non-temporal output stores (streaming write, keep L2 for reads)
__global__ __launch_bounds__(256, 4) void SequenceBucketPreprocessor_kernel(
    const float* __restrict__ features,    // (B,T,F)
    const float* __restrict__ thresholds,  // (S,KMAX)
    const int*   __restrict__ slot_ids,    // (S,)
    int*         __restrict__ out)         // (B,T,S) int32
{
    const int s   = threadIdx.x;                 // one s per thread (S==256==blockDim)
    const int bt0 = blockIdx.x * T_PER_BLOCK;    // first flattened (b*T+t) index

    // This thread's 32 thresholds -> registers (128B/lane, L1/L2-hot after warmup)
    float thr[KMAX];
    const float4* trow = reinterpret_cast<const float4*>(thresholds + s * KMAX);
    #pragma unroll
    for (int q = 0; q < KMAX / 4; ++q) {
        float4 t4 = trow[q];
        thr[q * 4 + 0] = t4.x;
        thr[q * 4 + 1] = t4.y;
        thr[q * 4 + 2] = t4.z;
        thr[q * 4 + 3] = t4.w;
    }
    const int slot = slot_ids[s];

    // Issue all 16 gathers before any use: 16 outstanding global_load_dword,
    // latency hidden behind one wait instead of 4 dependent groups.
    float v[T_PER_BLOCK];
    const float* fbase = features + (long)bt0 * F + slot;
    #pragma unroll
    for (int j = 0; j < T_PER_BLOCK; ++j)
        v[j] = fbase[j * F];

    int c[T_PER_BLOCK];
    #pragma unroll
    for (int j = 0; j < T_PER_BLOCK; ++j) c[j] = 0;

    #pragma unroll
    for (int k = 0; k < KMAX; ++k) {
        #pragma unroll
        for (int j = 0; j < T_PER_BLOCK; ++j)
            c[j] += (thr[k] <= v[j]);
    }

    // Coalesced streaming stores along s (out is write-only; nt keeps L2 clean)
    #pragma unroll
    for (int j = 0; j < T_PER_BLOCK; ++j)
        __builtin_nontemporal_store(c[j], out + (bt0 + j) * S + s);
}

extern "C" void kernel_launch(void* const* d_in, const int* in_sizes, int n_in,
                              void* d_out, int out_size, void* d_ws, size_t ws_size,
                              hipStream_t stream) {
    const float* features   = (const float*)d_in[0];  // (B,T,F) f32
    const float* thresholds = (const float*)d_in[1];  // (S,KMAX) f32
    const int*   slot_ids   = (const int*)d_in[2];    // (S,) i32
    // d_in[3] = bucket_nums: not needed (encoded in +inf padding of thresholds)
    int* out = (int*)d_out;                            // (B,T,S) i32

    const int n_bt   = B * T;                          // 16384
    const int blocks = n_bt / T_PER_BLOCK;             // 1024 = 4 blocks/CU
    SequenceBucketPreprocessor_kernel<<<dim3(blocks), dim3(S), 0, stream>>>(
        features, thresholds, slot_ids, out);
}